// Round 3
// baseline (172.897 us; speedup 1.0000x reference)
//
#include <hip/hip_runtime.h>

// VQ lookup: argmin_k ||z - c_k||^2 then gather codebook rows.
// N = 32768 queries, D = 128, K = 1024, fp32.
// score(q,k) = csq[k] - 2*dot(z_q, c_k)  (z_sq constant per query, dropped)
//
// Round-3 structure: lane = query. Block = 256 thr (4 waves), 64 queries.
// Lane holds its full z-row in 128 VGPRs (one-time LDS-transpose stage).
// Wave w scans k in [w*256, w*256+256); codebook addresses are wave-uniform
// (readfirstlane) -> scalar s_load_dwordx16 into SGPRs -> v_fmac_f32 with
// SGPR broadcast operand. Inner loop: 512 FMA / 0 LDS / 0 VMEM.

#define NQ 32768
#define DIM 128
#define KCB 1024
#define QB 64
#define NW 4
#define KSL (KCB / NW)   // 256 k per wave
#define ZSTRIDE 130      // dwords; even -> 8B-aligned float2, bank-spread 2-way

__global__ __launch_bounds__(256) void vq_csq_kernel(const float* __restrict__ cb,
                                                     float* __restrict__ csq) {
    int k = blockIdx.x * blockDim.x + threadIdx.x;
    if (k < KCB) {
        const float4* row = (const float4*)(cb + (size_t)k * DIM);
        float s = 0.f;
        #pragma unroll
        for (int i = 0; i < DIM / 4; ++i) {
            float4 v = row[i];
            s += v.x * v.x + v.y * v.y + v.z * v.z + v.w * v.w;
        }
        csq[k] = s;
    }
}

__global__ __launch_bounds__(256, 3) void vq_main_kernel(const float* __restrict__ z,
                                                         const float* __restrict__ cb,
                                                         const float* __restrict__ csq,
                                                         float* __restrict__ out) {
    __shared__ float zs[QB * ZSTRIDE];   // 33.3 KB (dead after prologue)
    __shared__ float red_v[NW][QB];
    __shared__ int   red_i[NW][QB];
    __shared__ int   kmin_s[QB];

    const int t    = threadIdx.x;
    const int lane = t & 63;
    const int w    = t >> 6;
    const int qbase = blockIdx.x * QB;

    // ---- prologue: coalesced global -> LDS (row stride 130 dwords) ----
    {
        const float2* src = (const float2*)(z + (size_t)qbase * DIM);
        #pragma unroll
        for (int i = 0; i < 16; ++i) {
            int g = t + 256 * i;                 // f2 index 0..4095
            float2 v = src[g];
            int row = g >> 6, col = g & 63;      // 64 f2 per row
            *(float2*)&zs[row * ZSTRIDE + col * 2] = v;
        }
    }
    __syncthreads();

    // ---- my query row -> 128 VGPRs (2-way bank pattern = free) ----
    float zr[DIM];
    #pragma unroll
    for (int i = 0; i < 64; ++i) {
        float2 v = *(const float2*)&zs[lane * ZSTRIDE + i * 2];
        zr[2 * i]     = v.x;
        zr[2 * i + 1] = v.y;
    }

    float minv = 3.4e38f;
    int   mini = 0;

    // wave-uniform k-slice base (forced into SGPR)
    const int wbase = __builtin_amdgcn_readfirstlane(w * KSL);

    #pragma unroll 1
    for (int kg = 0; kg < KSL / 4; ++kg) {
        const int k0 = wbase + kg * 4;                      // uniform
        const float* __restrict__ cp = cb + (size_t)k0 * DIM;
        const float4 cs = *(const float4*)(csq + k0);       // s_load_dwordx4

        float a0 = 0.f, a1 = 0.f, a2 = 0.f, a3 = 0.f;
        #pragma unroll
        for (int d = 0; d < DIM; ++d) {
            a0 = fmaf(zr[d], cp[d], a0);
            a1 = fmaf(zr[d], cp[DIM + d], a1);
            a2 = fmaf(zr[d], cp[2 * DIM + d], a2);
            a3 = fmaf(zr[d], cp[3 * DIM + d], a3);
        }

        const float s0 = fmaf(-2.f, a0, cs.x);
        const float s1 = fmaf(-2.f, a1, cs.y);
        const float s2 = fmaf(-2.f, a2, cs.z);
        const float s3 = fmaf(-2.f, a3, cs.w);
        // ascending k, strict < keeps earliest index
        if (s0 < minv) { minv = s0; mini = k0 + 0; }
        if (s1 < minv) { minv = s1; mini = k0 + 1; }
        if (s2 < minv) { minv = s2; mini = k0 + 2; }
        if (s3 < minv) { minv = s3; mini = k0 + 3; }
    }

    // ---- cross-wave argmin (4 candidates per query) ----
    red_v[w][lane] = minv;
    red_i[w][lane] = mini;
    __syncthreads();
    if (w == 0) {
        float bv = red_v[0][lane];
        int   bi = red_i[0][lane];
        #pragma unroll
        for (int x = 1; x < NW; ++x) {
            float v  = red_v[x][lane];
            int   ii = red_i[x][lane];
            if (v < bv || (v == bv && ii < bi)) { bv = v; bi = ii; }
        }
        kmin_s[lane] = bi;
    }
    __syncthreads();

    // ---- gather winning codebook rows ----
    {
        const int r  = t >> 2;
        const int c0 = t & 3;
        const float4* src = (const float4*)(cb + (size_t)kmin_s[r] * DIM);
        float4*       dst = (float4*)(out + (size_t)(qbase + r) * DIM);
        #pragma unroll
        for (int i = 0; i < 8; ++i) dst[c0 + 4 * i] = src[c0 + 4 * i];
    }
}

extern "C" void kernel_launch(void* const* d_in, const int* in_sizes, int n_in,
                              void* d_out, int out_size, void* d_ws, size_t ws_size,
                              hipStream_t stream) {
    const float* z  = (const float*)d_in[0];   // inputs [32,32,32,128]
    const float* cb = (const float*)d_in[1];   // codebook [1024,128]
    float* csq = (float*)d_ws;                 // 1024 floats scratch
    float* out = (float*)d_out;

    vq_csq_kernel<<<KCB / 256, 256, 0, stream>>>(cb, csq);
    vq_main_kernel<<<NQ / QB, 256, 0, stream>>>(z, cb, csq, out);
}

// Round 4
// 70.627 us; speedup vs baseline: 2.4480x; 2.4480x over previous
//
#include <hip/hip_runtime.h>

// VQ lookup via bf16-split MFMA + top-2 + exact fp32 refine.
// N = 32768 queries, D = 128, K = 1024 codes, fp32 in/out.
// dot(z,c) ~= zh*ch + zh*cl + zl*ch  (3 accumulating bf16 MFMAs, fp32 acc)
// score = csq[k] - 2*dot  (z_sq constant per query, dropped)
// Each lane tracks top-2 (s,k) lex; exact fp32 refine of the 2 candidates.
//
// Block: 512 thr = 8 waves (qgrp = w>>2 in {0,1} x kgrp = w&3 in {0..3}).
// Block tile: 128 q (resident) x 128 k streamed (8 tiles covers K=1024).
// Wave tile: 64q x 32k = 8 MFMA 16x16 tiles, 3 passes, 4 ksteps of d=32.
// LDS tiles [row][128] bf16 with T2 XOR swizzle on the 16B-chunk index:
// byte = row*256 + ((chunk ^ (row&7))*16)  -- conflict-free reads+writes.

typedef __bf16 bf16x8_t __attribute__((ext_vector_type(8)));
typedef float f32x4_t __attribute__((ext_vector_type(4)));
typedef unsigned short us8_t __attribute__((ext_vector_type(8)));

#define NQ 32768
#define DIM 128
#define KCB 1024
#define QTI 128
#define KTI 128
#define NKT (KCB / KTI)

#define MFMA(a, b, c) __builtin_amdgcn_mfma_f32_16x16x32_bf16(a, b, c, 0, 0, 0)

__device__ __forceinline__ unsigned short bf16_rne(float f) {
    unsigned u = __float_as_uint(f);
    u = (u + 0x7FFFu + ((u >> 16) & 1u)) >> 16;
    return (unsigned short)u;
}

// convert 8 fp32 (chunk of row) -> bf16 hi/lo, store swizzled
__device__ __forceinline__ void stage_row_chunk(unsigned short* Hs, unsigned short* Ls,
                                                const float4* src, int row, int chunk) {
    float4 v0 = src[chunk * 2];
    float4 v1 = src[chunk * 2 + 1];
    float fv[8] = {v0.x, v0.y, v0.z, v0.w, v1.x, v1.y, v1.z, v1.w};
    us8_t hv, lv;
    #pragma unroll
    for (int j = 0; j < 8; ++j) {
        unsigned short h = bf16_rne(fv[j]);
        float hf = __uint_as_float((unsigned)h << 16);
        hv[j] = h;
        lv[j] = bf16_rne(fv[j] - hf);
    }
    int byt = row * 256 + ((chunk ^ (row & 7)) * 16);
    *(us8_t*)((char*)Hs + byt) = hv;
    *(us8_t*)((char*)Ls + byt) = lv;
}

__global__ __launch_bounds__(256) void vq_csq_kernel(const float* __restrict__ cb,
                                                     float* __restrict__ csq) {
    int k = blockIdx.x * blockDim.x + threadIdx.x;
    if (k < KCB) {
        const float4* row = (const float4*)(cb + (size_t)k * DIM);
        float s = 0.f;
        #pragma unroll
        for (int i = 0; i < DIM / 4; ++i) {
            float4 v = row[i];
            s += v.x * v.x + v.y * v.y + v.z * v.z + v.w * v.w;
        }
        csq[k] = s;
    }
}

__global__ __launch_bounds__(512, 1) void vq_mfma_kernel(const float* __restrict__ z,
                                                         const float* __restrict__ cb,
                                                         const float* __restrict__ csq,
                                                         float* __restrict__ out) {
    __shared__ unsigned short ZH[QTI * DIM];   // 32 KB each
    __shared__ unsigned short ZL[QTI * DIM];
    __shared__ unsigned short CH[KTI * DIM];
    __shared__ unsigned short CL[KTI * DIM];
    __shared__ float CSQ[KCB];                 // 4 KB
    __shared__ float4 RED[4][QTI];             // 8 KB
    __shared__ int KWIN[QTI];

    const int t = threadIdx.x;
    const int l = t & 63;
    const int w = t >> 6;
    const int kg = w & 3;       // wave's k-group (32 k each)
    const int qg = w >> 2;      // wave's q-group (64 q each)
    const int qbase = blockIdx.x * QTI;
    const int srow = t >> 2;    // staging: 4 threads per row
    const int scol = t & 3;

    if (t < KCB / 4) ((float4*)CSQ)[t] = ((const float4*)csq)[t];

    {   // stage resident z tile (hi/lo)
        const float4* zs = (const float4*)(z + (size_t)(qbase + srow) * DIM);
        #pragma unroll
        for (int i = 0; i < 4; ++i)
            stage_row_chunk(ZH, ZL, zs, srow, scol + 4 * i);
    }

    float s1[4], s2[4];
    int i1[4], i2[4];
    #pragma unroll
    for (int qt = 0; qt < 4; ++qt) { s1[qt] = 3.4e38f; s2[qt] = 3.4e38f; i1[qt] = 0; i2[qt] = 0; }

    for (int kt = 0; kt < NKT; ++kt) {
        __syncthreads();   // prev-iter readers done (kt=0: covers z/csq staging)
        {   // stage c tile kt (hi/lo)
            const float4* cs = (const float4*)(cb + (size_t)(kt * KTI + srow) * DIM);
            #pragma unroll
            for (int i = 0; i < 4; ++i)
                stage_row_chunk(CH, CL, cs, srow, scol + 4 * i);
        }
        __syncthreads();

        f32x4_t acc[2][4];
        #pragma unroll
        for (int mt = 0; mt < 2; ++mt)
            #pragma unroll
            for (int qt = 0; qt < 4; ++qt)
                acc[mt][qt] = (f32x4_t){0.f, 0.f, 0.f, 0.f};

        #pragma unroll
        for (int ks = 0; ks < 4; ++ks) {
            const int chunk = ks * 4 + (l >> 4);
            bf16x8_t ah[2], al[2], bh[4], bl[4];
            #pragma unroll
            for (int mt = 0; mt < 2; ++mt) {
                int row = kg * 32 + mt * 16 + (l & 15);
                int byt = row * 256 + ((chunk ^ (row & 7)) * 16);
                ah[mt] = *(bf16x8_t*)((char*)CH + byt);
                al[mt] = *(bf16x8_t*)((char*)CL + byt);
            }
            #pragma unroll
            for (int qt = 0; qt < 4; ++qt) {
                int row = qg * 64 + qt * 16 + (l & 15);
                int byt = row * 256 + ((chunk ^ (row & 7)) * 16);
                bh[qt] = *(bf16x8_t*)((char*)ZH + byt);
                bl[qt] = *(bf16x8_t*)((char*)ZL + byt);
            }
            #pragma unroll
            for (int mt = 0; mt < 2; ++mt)
                #pragma unroll
                for (int qt = 0; qt < 4; ++qt) {
                    acc[mt][qt] = MFMA(ah[mt], bh[qt], acc[mt][qt]);
                    acc[mt][qt] = MFMA(ah[mt], bl[qt], acc[mt][qt]);
                    acc[mt][qt] = MFMA(al[mt], bh[qt], acc[mt][qt]);
                }
        }

        // scores + per-lane top-2 (k ascending within lane; strict < keeps earliest)
        const int grp4 = (l >> 4) * 4;
        #pragma unroll
        for (int qt = 0; qt < 4; ++qt)
            #pragma unroll
            for (int mt = 0; mt < 2; ++mt)
                #pragma unroll
                for (int r = 0; r < 4; ++r) {
                    int k = kt * KTI + kg * 32 + mt * 16 + grp4 + r;
                    float s = fmaf(-2.f, acc[mt][qt][r], CSQ[k]);
                    if (s < s1[qt])      { s2[qt] = s1[qt]; i2[qt] = i1[qt]; s1[qt] = s; i1[qt] = k; }
                    else if (s < s2[qt]) { s2[qt] = s; i2[qt] = k; }
                }
    }

    // intra-wave lex merge across the 4 lane-groups holding the same q
    #pragma unroll
    for (int qt = 0; qt < 4; ++qt) {
        float a1 = s1[qt], a2 = s2[qt];
        int j1 = i1[qt], j2 = i2[qt];
        #pragma unroll
        for (int off = 16; off < 64; off <<= 1) {
            float b1 = __shfl_xor(a1, off);
            float b2 = __shfl_xor(a2, off);
            int m1 = __shfl_xor(j1, off);
            int m2 = __shfl_xor(j2, off);
            bool bw = (b1 < a1) || (b1 == a1 && m1 < j1);
            float w1 = bw ? b1 : a1; int x1 = bw ? m1 : j1;
            float lb = bw ? a1 : b1; int ly = bw ? j1 : m1;   // loser's best
            float ws = bw ? b2 : a2; int wy = bw ? m2 : j2;   // winner's 2nd
            bool sw = (lb < ws) || (lb == ws && ly < wy);
            a1 = w1; j1 = x1;
            a2 = sw ? lb : ws; j2 = sw ? ly : wy;
        }
        if (l < 16)
            RED[kg][qg * 64 + qt * 16 + l] =
                make_float4(a1, __int_as_float(j1), a2, __int_as_float(j2));
    }
    __syncthreads();

    // final merge across 4 k-groups + exact fp32 refine (one thread per q)
    if (t < QTI) {
        float4 e = RED[0][t];
        float a1 = e.x, a2 = e.z;
        int j1 = __float_as_int(e.y), j2 = __float_as_int(e.w);
        #pragma unroll
        for (int g = 1; g < 4; ++g) {
            float4 f = RED[g][t];
            float b1 = f.x, b2 = f.z;
            int m1 = __float_as_int(f.y), m2 = __float_as_int(f.w);
            bool bw = (b1 < a1) || (b1 == a1 && m1 < j1);
            float w1 = bw ? b1 : a1; int x1 = bw ? m1 : j1;
            float lb = bw ? a1 : b1; int ly = bw ? j1 : m1;
            float ws = bw ? b2 : a2; int wy = bw ? m2 : j2;
            bool sw = (lb < ws) || (lb == ws && ly < wy);
            a1 = w1; j1 = x1;
            a2 = sw ? lb : ws; j2 = sw ? ly : wy;
        }
        const float* zr = z + (size_t)(qbase + t) * DIM;
        const float* c1 = cb + (size_t)j1 * DIM;
        const float* c2 = cb + (size_t)j2 * DIM;
        float p1 = 0.f, q1 = 0.f, p2 = 0.f, q2 = 0.f;
        #pragma unroll
        for (int d = 0; d < DIM; d += 4) {
            float4 zv = *(const float4*)(zr + d);
            float4 u = *(const float4*)(c1 + d);
            float4 v = *(const float4*)(c2 + d);
            p1 = fmaf(zv.x, u.x, p1); q1 = fmaf(zv.y, u.y, q1);
            p1 = fmaf(zv.z, u.z, p1); q1 = fmaf(zv.w, u.w, q1);
            p2 = fmaf(zv.x, v.x, p2); q2 = fmaf(zv.y, v.y, q2);
            p2 = fmaf(zv.z, v.z, p2); q2 = fmaf(zv.w, v.w, q2);
        }
        float e1 = fmaf(-2.f, p1 + q1, CSQ[j1]);
        float e2 = fmaf(-2.f, p2 + q2, CSQ[j2]);
        KWIN[t] = (e1 < e2 || (e1 == e2 && j1 < j2)) ? j1 : j2;
    }
    __syncthreads();

    {   // gather winning codebook rows
        const float4* src = (const float4*)(cb + (size_t)KWIN[srow] * DIM);
        float4* dst = (float4*)(out + (size_t)(qbase + srow) * DIM);
        #pragma unroll
        for (int i = 0; i < 8; ++i) dst[scol + 4 * i] = src[scol + 4 * i];
    }
}

extern "C" void kernel_launch(void* const* d_in, const int* in_sizes, int n_in,
                              void* d_out, int out_size, void* d_ws, size_t ws_size,
                              hipStream_t stream) {
    const float* z  = (const float*)d_in[0];   // inputs [32,32,32,128]
    const float* cb = (const float*)d_in[1];   // codebook [1024,128]
    float* csq = (float*)d_ws;                 // 1024 floats scratch
    float* out = (float*)d_out;

    vq_csq_kernel<<<KCB / 256, 256, 0, stream>>>(cb, csq);
    vq_mfma_kernel<<<NQ / QTI, 512, 0, stream>>>(z, cb, csq, out);
}

// Round 5
// 61.058 us; speedup vs baseline: 2.8317x; 1.1567x over previous
//
#include <hip/hip_runtime.h>

// VQ lookup via bf16-split MFMA + top-2 + exact fp32 refine.
// N = 32768 queries, D = 128, K = 1024 codes, fp32 in/out.
// dot(z,c) ~= zh*ch + zh*cl + zl*ch  (3 accumulating bf16 MFMAs, fp32 acc)
// score = csq[k] - 2*dot ; per-lane top-2 (lex) ; exact fp32 refine of the 2.
//
// Round-5: codebook hi/lo split PRECOMPUTED once into d_ws in LDS-image order
// (XOR swizzle baked into the global layout) -> main kernel stages c-tiles via
// global_load_lds (no VALU, no ds_write). z-frags hoisted into 128 VGPRs once;
// per-kt DS traffic = 16 b128 a-frag reads + 2 broadcast csq reads.
// Block: 512 thr = 8 waves (kg = w&3 over 32k, qg = w>>2 over 64q).
// Tile: 128 q resident x 128 k streamed (8 tiles).

typedef __bf16 bf16x8_t __attribute__((ext_vector_type(8)));
typedef float f32x4_t __attribute__((ext_vector_type(4)));
typedef unsigned short us8_t __attribute__((ext_vector_type(8)));

#define NQ 32768
#define DIM 128
#define KCB 1024
#define QTI 128
#define KTI 128
#define NKT (KCB / KTI)
#define TILE_BYTES 65536   // CH image (32 KB) + CL image (32 KB) per k-tile

#define MFMA(a, b, c) __builtin_amdgcn_mfma_f32_16x16x32_bf16(a, b, c, 0, 0, 0)

__device__ __forceinline__ unsigned short bf16_rne(float f) {
    unsigned u = __float_as_uint(f);
    u = (u + 0x7FFFu + ((u >> 16) & 1u)) >> 16;
    return (unsigned short)u;
}

__device__ __forceinline__ void gload_lds16(const void* g, void* s) {
    __builtin_amdgcn_global_load_lds(
        (const __attribute__((address_space(1))) unsigned int*)g,
        (__attribute__((address_space(3))) unsigned int*)s, 16, 0, 0);
}

// convert 8 fp32 (chunk of row) -> bf16 hi/lo, store swizzled into LDS images
__device__ __forceinline__ void stage_row_chunk(unsigned short* Hs, unsigned short* Ls,
                                                const float4* src, int row, int chunk) {
    float4 v0 = src[chunk * 2];
    float4 v1 = src[chunk * 2 + 1];
    float fv[8] = {v0.x, v0.y, v0.z, v0.w, v1.x, v1.y, v1.z, v1.w};
    us8_t hv, lv;
    #pragma unroll
    for (int j = 0; j < 8; ++j) {
        unsigned short h = bf16_rne(fv[j]);
        float hf = __uint_as_float((unsigned)h << 16);
        hv[j] = h;
        lv[j] = bf16_rne(fv[j] - hf);
    }
    int byt = row * 256 + ((chunk ^ (row & 7)) * 16);
    *(us8_t*)((char*)Hs + byt) = hv;
    *(us8_t*)((char*)Ls + byt) = lv;
}

// ---- prep: csq + codebook hi/lo split in LDS-image (swizzled) global layout
__global__ __launch_bounds__(256) void vq_prep_kernel(const float* __restrict__ cb,
                                                      float* __restrict__ csq,
                                                      unsigned short* __restrict__ cws) {
    const int t = threadIdx.x;
    const int g = blockIdx.x * 16 + (t >> 4);   // code row 0..1023
    const int chunk = t & 15;
    const float4* src = (const float4*)(cb + (size_t)g * DIM);
    float4 v0 = src[chunk * 2], v1 = src[chunk * 2 + 1];
    float fv[8] = {v0.x, v0.y, v0.z, v0.w, v1.x, v1.y, v1.z, v1.w};
    us8_t hv, lv;
    float ss = 0.f;
    #pragma unroll
    for (int j = 0; j < 8; ++j) {
        ss = fmaf(fv[j], fv[j], ss);
        unsigned short h = bf16_rne(fv[j]);
        hv[j] = h;
        lv[j] = bf16_rne(fv[j] - __uint_as_float((unsigned)h << 16));
    }
    #pragma unroll
    for (int off = 1; off < 16; off <<= 1) ss += __shfl_xor(ss, off);
    if (chunk == 0) csq[g] = ss;
    const int kt = g >> 7, r = g & 127;
    char* base = (char*)cws + (size_t)kt * TILE_BYTES + r * 256 + ((chunk ^ (r & 7)) * 16);
    *(us8_t*)base = hv;               // CH image
    *(us8_t*)(base + 32768) = lv;     // CL image
}

__global__ __launch_bounds__(512, 2) void vq_mfma_kernel(const float* __restrict__ z,
                                                         const float* __restrict__ cb,
                                                         const unsigned short* __restrict__ cws,
                                                         const float* __restrict__ csq,
                                                         float* __restrict__ out) {
    __shared__ unsigned short ZHL[2 * QTI * DIM];   // 64 KB: ZH image | ZL image
    __shared__ unsigned short CHL[2 * KTI * DIM];   // 64 KB: CH image | CL image
    __shared__ float CSQ[KCB];                      // 4 KB
    __shared__ float4 RED[4][QTI];                  // 8 KB
    __shared__ int KWIN[QTI];

    unsigned short* const ZH = ZHL;
    unsigned short* const ZL = ZHL + QTI * DIM;

    const int t = threadIdx.x;
    const int l = t & 63;
    const int w = t >> 6;
    const int kg = w & 3;       // wave's k-group (32 k)
    const int qg = w >> 2;      // wave's q-group (64 q)
    const int qbase = blockIdx.x * QTI;
    const int srow = t >> 2;
    const int scol = t & 3;

    // issue c-tile-0 staging first; latency hides under z conversion
    {
        const char* src = (const char*)cws + w * 8192 + l * 16;
        char* dst = (char*)CHL + w * 8192;
        #pragma unroll
        for (int i = 0; i < 8; ++i)
            gload_lds16(src + i * 1024, dst + i * 1024);
    }

    if (t < KCB / 4) ((float4*)CSQ)[t] = ((const float4*)csq)[t];

    {   // stage z tile hi/lo (one-time VALU conversion)
        const float4* zs = (const float4*)(z + (size_t)(qbase + srow) * DIM);
        #pragma unroll
        for (int i = 0; i < 4; ++i)
            stage_row_chunk(ZH, ZL, zs, srow, scol + 4 * i);
    }

    asm volatile("s_waitcnt vmcnt(0)" ::: "memory");
    __syncthreads();

    // z fragments -> registers (invariant across all k-tiles): 128 VGPRs
    bf16x8_t bh[4][4], bl[4][4];
    #pragma unroll
    for (int qt = 0; qt < 4; ++qt)
        #pragma unroll
        for (int ks = 0; ks < 4; ++ks) {
            const int row = qg * 64 + qt * 16 + (l & 15);
            const int chunk = ks * 4 + (l >> 4);
            const int byt = row * 256 + ((chunk ^ (row & 7)) * 16);
            bh[qt][ks] = *(bf16x8_t*)((char*)ZH + byt);
            bl[qt][ks] = *(bf16x8_t*)((char*)ZL + byt);
        }

    float s1[4], s2[4];
    int i1[4], i2[4];
    #pragma unroll
    for (int qt = 0; qt < 4; ++qt) { s1[qt] = 3.4e38f; s2[qt] = 3.4e38f; i1[qt] = 0; i2[qt] = 0; }

    const int grp4 = (l >> 4) * 4;

    for (int kt = 0; kt < NKT; ++kt) {
        // CHL holds tile kt
        const float4 cs0 = *(const float4*)&CSQ[kt * KTI + kg * 32 + grp4];
        const float4 cs1 = *(const float4*)&CSQ[kt * KTI + kg * 32 + 16 + grp4];

        f32x4_t acc[2][4];
        #pragma unroll
        for (int mt = 0; mt < 2; ++mt)
            #pragma unroll
            for (int qt = 0; qt < 4; ++qt)
                acc[mt][qt] = (f32x4_t){0.f, 0.f, 0.f, 0.f};

        #pragma unroll
        for (int ks = 0; ks < 4; ++ks) {
            const int chunk = ks * 4 + (l >> 4);
            bf16x8_t ah[2], al[2];
            #pragma unroll
            for (int mt = 0; mt < 2; ++mt) {
                const int row = kg * 32 + mt * 16 + (l & 15);
                const int byt = row * 256 + ((chunk ^ (row & 7)) * 16);
                ah[mt] = *(bf16x8_t*)((char*)CHL + byt);
                al[mt] = *(bf16x8_t*)((char*)CHL + 32768 + byt);
            }
            #pragma unroll
            for (int mt = 0; mt < 2; ++mt)
                #pragma unroll
                for (int qt = 0; qt < 4; ++qt) {
                    acc[mt][qt] = MFMA(ah[mt], bh[qt][ks], acc[mt][qt]);
                    acc[mt][qt] = MFMA(ah[mt], bl[qt][ks], acc[mt][qt]);
                    acc[mt][qt] = MFMA(al[mt], bh[qt][ks], acc[mt][qt]);
                }
        }

        __syncthreads();   // all waves done reading CHL

        if (kt < NKT - 1) {   // issue next tile's staging; scores run under it
            const char* src = (const char*)cws + (size_t)(kt + 1) * TILE_BYTES + w * 8192 + l * 16;
            char* dst = (char*)CHL + w * 8192;
            #pragma unroll
            for (int i = 0; i < 8; ++i)
                gload_lds16(src + i * 1024, dst + i * 1024);
        }

        // scores + per-lane top-2 (ascending k; strict < keeps earliest)
        #pragma unroll
        for (int qt = 0; qt < 4; ++qt)
            #pragma unroll
            for (int mt = 0; mt < 2; ++mt)
                #pragma unroll
                for (int r = 0; r < 4; ++r) {
                    float cq = (mt == 0) ? ((const float*)&cs0)[r] : ((const float*)&cs1)[r];
                    int k = kt * KTI + kg * 32 + mt * 16 + grp4 + r;
                    float s = fmaf(-2.f, acc[mt][qt][r], cq);
                    if (s < s1[qt])      { s2[qt] = s1[qt]; i2[qt] = i1[qt]; s1[qt] = s; i1[qt] = k; }
                    else if (s < s2[qt]) { s2[qt] = s; i2[qt] = k; }
                }

        if (kt < NKT - 1) {
            asm volatile("s_waitcnt vmcnt(0)" ::: "memory");
            __syncthreads();
        }
    }

    // intra-wave lex merge across the 4 lane-groups holding the same q
    #pragma unroll
    for (int qt = 0; qt < 4; ++qt) {
        float a1 = s1[qt], a2 = s2[qt];
        int j1 = i1[qt], j2 = i2[qt];
        #pragma unroll
        for (int off = 16; off < 64; off <<= 1) {
            float b1 = __shfl_xor(a1, off);
            float b2 = __shfl_xor(a2, off);
            int m1 = __shfl_xor(j1, off);
            int m2 = __shfl_xor(j2, off);
            bool bw = (b1 < a1) || (b1 == a1 && m1 < j1);
            float w1 = bw ? b1 : a1; int x1 = bw ? m1 : j1;
            float lb = bw ? a1 : b1; int ly = bw ? j1 : m1;   // loser's best
            float ws = bw ? b2 : a2; int wy = bw ? m2 : j2;   // winner's 2nd
            bool sw = (lb < ws) || (lb == ws && ly < wy);
            a1 = w1; j1 = x1;
            a2 = sw ? lb : ws; j2 = sw ? ly : wy;
        }
        if (l < 16)
            RED[kg][qg * 64 + qt * 16 + l] =
                make_float4(a1, __int_as_float(j1), a2, __int_as_float(j2));
    }
    __syncthreads();

    // final merge across 4 k-groups + exact fp32 refine (one thread per q)
    if (t < QTI) {
        float4 e = RED[0][t];
        float a1 = e.x, a2 = e.z;
        int j1 = __float_as_int(e.y), j2 = __float_as_int(e.w);
        #pragma unroll
        for (int g = 1; g < 4; ++g) {
            float4 f = RED[g][t];
            float b1 = f.x, b2 = f.z;
            int m1 = __float_as_int(f.y), m2 = __float_as_int(f.w);
            bool bw = (b1 < a1) || (b1 == a1 && m1 < j1);
            float w1 = bw ? b1 : a1; int x1 = bw ? m1 : j1;
            float lb = bw ? a1 : b1; int ly = bw ? j1 : m1;
            float ws = bw ? b2 : a2; int wy = bw ? m2 : j2;
            bool sw = (lb < ws) || (lb == ws && ly < wy);
            a1 = w1; j1 = x1;
            a2 = sw ? lb : ws; j2 = sw ? ly : wy;
        }
        const float* zr = z + (size_t)(qbase + t) * DIM;
        const float* c1 = cb + (size_t)j1 * DIM;
        const float* c2 = cb + (size_t)j2 * DIM;
        float p1 = 0.f, q1 = 0.f, p2 = 0.f, q2 = 0.f;
        #pragma unroll
        for (int d = 0; d < DIM; d += 4) {
            float4 zv = *(const float4*)(zr + d);
            float4 u = *(const float4*)(c1 + d);
            float4 v = *(const float4*)(c2 + d);
            p1 = fmaf(zv.x, u.x, p1); q1 = fmaf(zv.y, u.y, q1);
            p1 = fmaf(zv.z, u.z, p1); q1 = fmaf(zv.w, u.w, q1);
            p2 = fmaf(zv.x, v.x, p2); q2 = fmaf(zv.y, v.y, q2);
            p2 = fmaf(zv.z, v.z, p2); q2 = fmaf(zv.w, v.w, q2);
        }
        float e1 = fmaf(-2.f, p1 + q1, CSQ[j1]);
        float e2 = fmaf(-2.f, p2 + q2, CSQ[j2]);
        KWIN[t] = (e1 < e2 || (e1 == e2 && j1 < j2)) ? j1 : j2;
    }
    __syncthreads();

    {   // gather winning codebook rows
        const float4* src = (const float4*)(cb + (size_t)KWIN[srow] * DIM);
        float4* dst = (float4*)(out + (size_t)(qbase + srow) * DIM);
        #pragma unroll
        for (int i = 0; i < 8; ++i) dst[scol + 4 * i] = src[scol + 4 * i];
    }
}

extern "C" void kernel_launch(void* const* d_in, const int* in_sizes, int n_in,
                              void* d_out, int out_size, void* d_ws, size_t ws_size,
                              hipStream_t stream) {
    const float* z  = (const float*)d_in[0];   // inputs [32,32,32,128]
    const float* cb = (const float*)d_in[1];   // codebook [1024,128]
    float* csq = (float*)d_ws;                             // 4 KB
    unsigned short* cws = (unsigned short*)((char*)d_ws + 4096);  // 512 KB split codebook
    float* out = (float*)d_out;

    vq_prep_kernel<<<KCB / 16, 256, 0, stream>>>(cb, csq, cws);
    vq_mfma_kernel<<<NQ / QTI, 512, 0, stream>>>(z, cb, cws, csq, out);
}

// Round 6
// 56.840 us; speedup vs baseline: 3.0418x; 1.0742x over previous
//
#include <hip/hip_runtime.h>

// VQ lookup via bf16-split MFMA + top-2 + exact fp32 refine.
// N = 32768 queries, D = 128, K = 1024 codes, fp32 in/out.
// dot(z,c) ~= zh*ch + zh*cl + zl*ch  (3 accumulating bf16 MFMAs, fp32 acc)
// score = csq[k] - 2*dot ; per-lane top-2 (lex) ; exact fp32 refine of the 2.
//
// Round-6: z-fragments loaded DIRECTLY from global in MFMA B-frag layout,
// converted hi/lo in-register, pinned with asm so the compiler cannot sink
// them back to memory (round-5 failure: VGPR=128 showed the hoist was lost).
// No z LDS. CHL double-buffered (2x64KB): stage kt+1 via global_load_lds at
// loop top, compute under it, ONE barrier per kt (implicit vmcnt drain).
// Per-kt DS traffic: 16 swizzled b128 a-frag reads + 2 broadcast csq reads.

typedef __bf16 bf16x8_t __attribute__((ext_vector_type(8)));
typedef float f32x4_t __attribute__((ext_vector_type(4)));
typedef unsigned short us8_t __attribute__((ext_vector_type(8)));

#define NQ 32768
#define DIM 128
#define KCB 1024
#define QTI 128
#define KTI 128
#define NKT (KCB / KTI)
#define TILE_BYTES 65536   // CH image (32 KB) + CL image (32 KB) per k-tile

#define MFMA(a, b, c) __builtin_amdgcn_mfma_f32_16x16x32_bf16(a, b, c, 0, 0, 0)

__device__ __forceinline__ unsigned short bf16_rne(float f) {
    unsigned u = __float_as_uint(f);
    u = (u + 0x7FFFu + ((u >> 16) & 1u)) >> 16;
    return (unsigned short)u;
}

__device__ __forceinline__ void gload_lds16(const void* g, void* s) {
    __builtin_amdgcn_global_load_lds(
        (const __attribute__((address_space(1))) unsigned int*)g,
        (__attribute__((address_space(3))) unsigned int*)s, 16, 0, 0);
}

__device__ __forceinline__ bf16x8_t as_bf(f32x4_t v) {
    union { f32x4_t f; bf16x8_t b; } u; u.f = v; return u.b;
}

// 8 fp32 -> hi/lo bf16 packs (as f32x4 register images)
__device__ __forceinline__ void cvt8(const float4 a, const float4 b,
                                     f32x4_t* hi, f32x4_t* lo) {
    float fv[8] = {a.x, a.y, a.z, a.w, b.x, b.y, b.z, b.w};
    us8_t hv, lv;
    #pragma unroll
    for (int j = 0; j < 8; ++j) {
        unsigned short h = bf16_rne(fv[j]);
        hv[j] = h;
        lv[j] = bf16_rne(fv[j] - __uint_as_float((unsigned)h << 16));
    }
    union { us8_t u; f32x4_t f; } ch, cl;
    ch.u = hv; cl.u = lv;
    *hi = ch.f; *lo = cl.f;
}

// ---- prep: csq + codebook hi/lo split in LDS-image (swizzled) global layout
__global__ __launch_bounds__(256) void vq_prep_kernel(const float* __restrict__ cb,
                                                      float* __restrict__ csq,
                                                      unsigned short* __restrict__ cws) {
    const int t = threadIdx.x;
    const int g = blockIdx.x * 16 + (t >> 4);   // code row 0..1023
    const int chunk = t & 15;
    const float4* src = (const float4*)(cb + (size_t)g * DIM);
    float4 v0 = src[chunk * 2], v1 = src[chunk * 2 + 1];
    float fv[8] = {v0.x, v0.y, v0.z, v0.w, v1.x, v1.y, v1.z, v1.w};
    us8_t hv, lv;
    float ss = 0.f;
    #pragma unroll
    for (int j = 0; j < 8; ++j) {
        ss = fmaf(fv[j], fv[j], ss);
        unsigned short h = bf16_rne(fv[j]);
        hv[j] = h;
        lv[j] = bf16_rne(fv[j] - __uint_as_float((unsigned)h << 16));
    }
    #pragma unroll
    for (int off = 1; off < 16; off <<= 1) ss += __shfl_xor(ss, off);
    if (chunk == 0) csq[g] = ss;
    const int kt = g >> 7, r = g & 127;
    char* base = (char*)cws + (size_t)kt * TILE_BYTES + r * 256 + ((chunk ^ (r & 7)) * 16);
    *(us8_t*)base = hv;               // CH image
    *(us8_t*)(base + 32768) = lv;     // CL image
}

__global__ __launch_bounds__(512, 2) void vq_mfma_kernel(const float* __restrict__ z,
                                                         const float* __restrict__ cb,
                                                         const unsigned short* __restrict__ cws,
                                                         const float* __restrict__ csq,
                                                         float* __restrict__ out) {
    __shared__ unsigned short CHL[2 * 2 * KTI * DIM];   // 128 KB: 2 bufs x (CH|CL)
    __shared__ float CSQ[KCB];                          // 4 KB
    __shared__ float4 RED[4][QTI];                      // 8 KB
    __shared__ int KWIN[QTI];

    const int t = threadIdx.x;
    const int l = t & 63;
    const int w = t >> 6;
    const int kg = w & 3;       // wave's k-group (32 k)
    const int qg = w >> 2;      // wave's q-group (64 q)
    const int qbase = blockIdx.x * QTI;
    const int srow = t >> 2;
    const int scol = t & 3;

    // issue c-tile-0 staging into buf0; latency hides under z conversion
    {
        const char* src = (const char*)cws + w * 8192 + l * 16;
        char* dst = (char*)CHL + w * 8192;
        #pragma unroll
        for (int i = 0; i < 8; ++i)
            gload_lds16(src + i * 1024, dst + i * 1024);
    }

    if (t < KCB / 4) ((float4*)CSQ)[t] = ((const float4*)csq)[t];

    // ---- z fragments: DIRECT global load in B-frag layout, convert hi/lo ----
    // B-frag: lane l holds z[qg*64+qt*16+(l&15)][chunk*8 .. +8), chunk=ks*4+(l>>4)
    f32x4_t zh[4][4], zl[4][4];
    #pragma unroll
    for (int qt = 0; qt < 4; ++qt)
        #pragma unroll
        for (int ks = 0; ks < 4; ++ks) {
            const int qrow = qg * 64 + qt * 16 + (l & 15);
            const int chunk = ks * 4 + (l >> 4);
            const float4* p = (const float4*)(z + (size_t)(qbase + qrow) * DIM + chunk * 8);
            cvt8(p[0], p[1], &zh[qt][ks], &zl[qt][ks]);
        }
    // pin: opaque redefinition prevents remat/sink of the 32 fragments
    #pragma unroll
    for (int qt = 0; qt < 4; ++qt)
        #pragma unroll
        for (int ks = 0; ks < 4; ++ks)
            asm volatile("" : "+v"(zh[qt][ks]), "+v"(zl[qt][ks]));

    __syncthreads();   // drains tile-0 staging (implicit vmcnt(0)) for all waves

    float s1[4], s2[4];
    int i1[4], i2[4];
    #pragma unroll
    for (int qt = 0; qt < 4; ++qt) { s1[qt] = 3.4e38f; s2[qt] = 3.4e38f; i1[qt] = 0; i2[qt] = 0; }

    const int grp4 = (l >> 4) * 4;

    #pragma unroll 1
    for (int kt = 0; kt < NKT; ++kt) {
        const int cur = kt & 1;
        char* const buf = (char*)CHL + cur * TILE_BYTES;

        if (kt < NKT - 1) {   // stage next tile into other buffer; compute hides it
            const char* src = (const char*)cws + (size_t)(kt + 1) * TILE_BYTES + w * 8192 + l * 16;
            char* dst = (char*)CHL + (cur ^ 1) * TILE_BYTES + w * 8192;
            #pragma unroll
            for (int i = 0; i < 8; ++i)
                gload_lds16(src + i * 1024, dst + i * 1024);
        }

        const float4 cs0 = *(const float4*)&CSQ[kt * KTI + kg * 32 + grp4];
        const float4 cs1 = *(const float4*)&CSQ[kt * KTI + kg * 32 + 16 + grp4];

        f32x4_t acc[2][4];
        #pragma unroll
        for (int mt = 0; mt < 2; ++mt)
            #pragma unroll
            for (int qt = 0; qt < 4; ++qt)
                acc[mt][qt] = (f32x4_t){0.f, 0.f, 0.f, 0.f};

        #pragma unroll
        for (int ks = 0; ks < 4; ++ks) {
            const int chunk = ks * 4 + (l >> 4);
            bf16x8_t ah[2], al[2];
            #pragma unroll
            for (int mt = 0; mt < 2; ++mt) {
                const int row = kg * 32 + mt * 16 + (l & 15);
                const int byt = row * 256 + ((chunk ^ (row & 7)) * 16);
                ah[mt] = *(bf16x8_t*)(buf + byt);
                al[mt] = *(bf16x8_t*)(buf + 32768 + byt);
            }
            #pragma unroll
            for (int mt = 0; mt < 2; ++mt)
                #pragma unroll
                for (int qt = 0; qt < 4; ++qt) {
                    acc[mt][qt] = MFMA(ah[mt], as_bf(zh[qt][ks]), acc[mt][qt]);
                    acc[mt][qt] = MFMA(ah[mt], as_bf(zl[qt][ks]), acc[mt][qt]);
                    acc[mt][qt] = MFMA(al[mt], as_bf(zh[qt][ks]), acc[mt][qt]);
                }
        }

        // scores + per-lane top-2 (ascending k; strict < keeps earliest)
        #pragma unroll
        for (int qt = 0; qt < 4; ++qt)
            #pragma unroll
            for (int mt = 0; mt < 2; ++mt)
                #pragma unroll
                for (int r = 0; r < 4; ++r) {
                    float cq = (mt == 0) ? ((const float*)&cs0)[r] : ((const float*)&cs1)[r];
                    int k = kt * KTI + kg * 32 + mt * 16 + grp4 + r;
                    float s = fmaf(-2.f, acc[mt][qt][r], cq);
                    if (s < s1[qt])      { s2[qt] = s1[qt]; i2[qt] = i1[qt]; s1[qt] = s; i1[qt] = k; }
                    else if (s < s2[qt]) { s2[qt] = s; i2[qt] = k; }
                }

        __syncthreads();   // implicit vmcnt(0): next tile staged; readers of buf done
    }

    // intra-wave lex merge across the 4 lane-groups holding the same q
    #pragma unroll
    for (int qt = 0; qt < 4; ++qt) {
        float a1 = s1[qt], a2 = s2[qt];
        int j1 = i1[qt], j2 = i2[qt];
        #pragma unroll
        for (int off = 16; off < 64; off <<= 1) {
            float b1 = __shfl_xor(a1, off);
            float b2 = __shfl_xor(a2, off);
            int m1 = __shfl_xor(j1, off);
            int m2 = __shfl_xor(j2, off);
            bool bw = (b1 < a1) || (b1 == a1 && m1 < j1);
            float w1 = bw ? b1 : a1; int x1 = bw ? m1 : j1;
            float lb = bw ? a1 : b1; int ly = bw ? j1 : m1;   // loser's best
            float ws = bw ? b2 : a2; int wy = bw ? m2 : j2;   // winner's 2nd
            bool sw = (lb < ws) || (lb == ws && ly < wy);
            a1 = w1; j1 = x1;
            a2 = sw ? lb : ws; j2 = sw ? ly : wy;
        }
        if (l < 16)
            RED[kg][qg * 64 + qt * 16 + l] =
                make_float4(a1, __int_as_float(j1), a2, __int_as_float(j2));
    }
    __syncthreads();

    // final merge across 4 k-groups + exact fp32 refine (one thread per q)
    if (t < QTI) {
        float4 e = RED[0][t];
        float a1 = e.x, a2 = e.z;
        int j1 = __float_as_int(e.y), j2 = __float_as_int(e.w);
        #pragma unroll
        for (int g = 1; g < 4; ++g) {
            float4 f = RED[g][t];
            float b1 = f.x, b2 = f.z;
            int m1 = __float_as_int(f.y), m2 = __float_as_int(f.w);
            bool bw = (b1 < a1) || (b1 == a1 && m1 < j1);
            float w1 = bw ? b1 : a1; int x1 = bw ? m1 : j1;
            float lb = bw ? a1 : b1; int ly = bw ? j1 : m1;
            float ws = bw ? b2 : a2; int wy = bw ? m2 : j2;
            bool sw = (lb < ws) || (lb == ws && ly < wy);
            a1 = w1; j1 = x1;
            a2 = sw ? lb : ws; j2 = sw ? ly : wy;
        }
        const float* zr = z + (size_t)(qbase + t) * DIM;
        const float* c1 = cb + (size_t)j1 * DIM;
        const float* c2 = cb + (size_t)j2 * DIM;
        float p1 = 0.f, q1 = 0.f, p2 = 0.f, q2 = 0.f;
        #pragma unroll
        for (int d = 0; d < DIM; d += 4) {
            float4 zv = *(const float4*)(zr + d);
            float4 u = *(const float4*)(c1 + d);
            float4 v = *(const float4*)(c2 + d);
            p1 = fmaf(zv.x, u.x, p1); q1 = fmaf(zv.y, u.y, q1);
            p1 = fmaf(zv.z, u.z, p1); q1 = fmaf(zv.w, u.w, q1);
            p2 = fmaf(zv.x, v.x, p2); q2 = fmaf(zv.y, v.y, q2);
            p2 = fmaf(zv.z, v.z, p2); q2 = fmaf(zv.w, v.w, q2);
        }
        float e1 = fmaf(-2.f, p1 + q1, CSQ[j1]);
        float e2 = fmaf(-2.f, p2 + q2, CSQ[j2]);
        KWIN[t] = (e1 < e2 || (e1 == e2 && j1 < j2)) ? j1 : j2;
    }
    __syncthreads();

    {   // gather winning codebook rows
        const float4* src = (const float4*)(cb + (size_t)KWIN[srow] * DIM);
        float4* dst = (float4*)(out + (size_t)(qbase + srow) * DIM);
        #pragma unroll
        for (int i = 0; i < 8; ++i) dst[scol + 4 * i] = src[scol + 4 * i];
    }
}

extern "C" void kernel_launch(void* const* d_in, const int* in_sizes, int n_in,
                              void* d_out, int out_size, void* d_ws, size_t ws_size,
                              hipStream_t stream) {
    const float* z  = (const float*)d_in[0];   // inputs [32,32,32,128]
    const float* cb = (const float*)d_in[1];   // codebook [1024,128]
    float* csq = (float*)d_ws;                             // 4 KB
    unsigned short* cws = (unsigned short*)((char*)d_ws + 4096);  // 512 KB split codebook
    float* out = (float*)d_out;

    vq_prep_kernel<<<KCB / 16, 256, 0, stream>>>(cb, csq, cws);
    vq_mfma_kernel<<<NQ / QTI, 512, 0, stream>>>(z, cb, cws, csq, out);
}

// Round 8
// 51.490 us; speedup vs baseline: 3.3579x; 1.1039x over previous
//
#include <hip/hip_runtime.h>

// VQ lookup via bf16-split MFMA + top-2 + exact fp32 refine.
// N = 32768 queries, D = 128, K = 1024 codes, fp32 in/out.
// dot(z,c) ~= zh*ch + zh*cl + zl*ch  (3 accumulating bf16 MFMAs, fp32 acc)
// score = csq[k] - 2*dot ; per-lane top-2 (lex) ; exact fp32 refine of the 2.
//
// Round-8 = round-7 with the LDS double-buffer size bug fixed:
// CHL must be 2 (dbuf) x 2 (H|L) x KTI x DIM shorts = 64 KB. Round 7 declared
// half that, so odd tiles wrote past the array into CSQ/RED -> wrong argmins.
// Structure: QTI=64, KTI=64 (16 tiles), grid 512 = 2 blocks/CU, 4 waves/SIMD.
// z-frags pinned in 64 VGPRs; one barrier per kt; staging via global_load_lds.

typedef __bf16 bf16x8_t __attribute__((ext_vector_type(8)));
typedef float f32x4_t __attribute__((ext_vector_type(4)));
typedef unsigned short us8_t __attribute__((ext_vector_type(8)));

#define NQ 32768
#define DIM 128
#define KCB 1024
#define QTI 64
#define KTI 64
#define NKT (KCB / KTI)
#define TILE_BYTES 32768   // CH image (16 KB) + CL image (16 KB) per k-tile

#define MFMA(a, b, c) __builtin_amdgcn_mfma_f32_16x16x32_bf16(a, b, c, 0, 0, 0)

__device__ __forceinline__ unsigned short bf16_rne(float f) {
    unsigned u = __float_as_uint(f);
    u = (u + 0x7FFFu + ((u >> 16) & 1u)) >> 16;
    return (unsigned short)u;
}

__device__ __forceinline__ void gload_lds16(const void* g, void* s) {
    __builtin_amdgcn_global_load_lds(
        (const __attribute__((address_space(1))) unsigned int*)g,
        (__attribute__((address_space(3))) unsigned int*)s, 16, 0, 0);
}

__device__ __forceinline__ bf16x8_t as_bf(f32x4_t v) {
    union { f32x4_t f; bf16x8_t b; } u; u.f = v; return u.b;
}

// 8 fp32 -> hi/lo bf16 packs via native casts (v_cvt_pk_bf16_f32)
__device__ __forceinline__ void cvt8(const float4 a, const float4 b,
                                     f32x4_t* hi, f32x4_t* lo) {
    float fv[8] = {a.x, a.y, a.z, a.w, b.x, b.y, b.z, b.w};
    bf16x8_t hb, lb;
    #pragma unroll
    for (int j = 0; j < 8; ++j) {
        __bf16 h = (__bf16)fv[j];
        hb[j] = h;
        lb[j] = (__bf16)(fv[j] - (float)h);
    }
    union { bf16x8_t b; f32x4_t f; } uh, ul;
    uh.b = hb; ul.b = lb;
    *hi = uh.f; *lo = ul.f;
}

// ---- prep: csq + codebook hi/lo split in LDS-image (swizzled) global layout
__global__ __launch_bounds__(256) void vq_prep_kernel(const float* __restrict__ cb,
                                                      float* __restrict__ csq,
                                                      unsigned short* __restrict__ cws) {
    const int t = threadIdx.x;
    const int g = blockIdx.x * 16 + (t >> 4);   // code row 0..1023
    const int chunk = t & 15;
    const float4* src = (const float4*)(cb + (size_t)g * DIM);
    float4 v0 = src[chunk * 2], v1 = src[chunk * 2 + 1];
    float fv[8] = {v0.x, v0.y, v0.z, v0.w, v1.x, v1.y, v1.z, v1.w};
    us8_t hv, lv;
    float ss = 0.f;
    #pragma unroll
    for (int j = 0; j < 8; ++j) {
        ss = fmaf(fv[j], fv[j], ss);
        unsigned short h = bf16_rne(fv[j]);
        hv[j] = h;
        lv[j] = bf16_rne(fv[j] - __uint_as_float((unsigned)h << 16));
    }
    #pragma unroll
    for (int off = 1; off < 16; off <<= 1) ss += __shfl_xor(ss, off);
    if (chunk == 0) csq[g] = ss;
    const int kt = g >> 6, r = g & 63;
    char* base = (char*)cws + (size_t)kt * TILE_BYTES + r * 256 + ((chunk ^ (r & 7)) * 16);
    *(us8_t*)base = hv;               // CH image
    *(us8_t*)(base + 16384) = lv;     // CL image
}

__global__ __launch_bounds__(512, 4) void vq_mfma_kernel(const float* __restrict__ z,
                                                         const float* __restrict__ cb,
                                                         const unsigned short* __restrict__ cws,
                                                         const float* __restrict__ csq,
                                                         float* __restrict__ out) {
    __shared__ unsigned short CHL[2 * 2 * KTI * DIM];   // 64 KB: 2 bufs x (CH|CL)
    __shared__ float CSQ[KCB];                          // 4 KB
    __shared__ float4 RED[4][QTI];                      // 4 KB
    __shared__ int KWIN[QTI];                           // 256 B

    const int t = threadIdx.x;
    const int l = t & 63;
    const int w = t >> 6;
    const int kg = w & 3;       // wave's k-group (16 k per tile)
    const int qgrp = w >> 2;    // wave's q-group (32 q each)
    const int qbase = blockIdx.x * QTI;

    // issue c-tile-0 staging into buf0; latency hides under z conversion
    {
        const char* src = (const char*)cws + w * 4096 + l * 16;
        char* dst = (char*)CHL + w * 4096;
        #pragma unroll
        for (int i = 0; i < 4; ++i)
            gload_lds16(src + i * 1024, dst + i * 1024);
    }

    if (t < KCB / 4) ((float4*)CSQ)[t] = ((const float4*)csq)[t];

    // ---- z fragments: direct global load in B-frag layout, hi/lo in-register
    f32x4_t zh[2][4], zl[2][4];
    #pragma unroll
    for (int qt = 0; qt < 2; ++qt)
        #pragma unroll
        for (int ks = 0; ks < 4; ++ks) {
            const int qrow = qgrp * 32 + qt * 16 + (l & 15);
            const int chunk = ks * 4 + (l >> 4);
            const float4* p = (const float4*)(z + (size_t)(qbase + qrow) * DIM + chunk * 8);
            cvt8(p[0], p[1], &zh[qt][ks], &zl[qt][ks]);
        }
    #pragma unroll
    for (int qt = 0; qt < 2; ++qt)
        #pragma unroll
        for (int ks = 0; ks < 4; ++ks)
            asm volatile("" : "+v"(zh[qt][ks]), "+v"(zl[qt][ks]));

    asm volatile("s_waitcnt vmcnt(0)" ::: "memory");
    __syncthreads();   // tile-0 staging drained for all waves

    float s1[2], s2[2];
    int i1[2], i2[2];
    #pragma unroll
    for (int qt = 0; qt < 2; ++qt) { s1[qt] = 3.4e38f; s2[qt] = 3.4e38f; i1[qt] = 0; i2[qt] = 0; }

    const int grp4 = (l >> 4) * 4;

    #pragma unroll 1
    for (int kt = 0; kt < NKT; ++kt) {
        const int cur = kt & 1;
        char* const buf = (char*)CHL + cur * TILE_BYTES;

        if (kt < NKT - 1) {   // stage next tile into other buffer
            const char* src = (const char*)cws + (size_t)(kt + 1) * TILE_BYTES + w * 4096 + l * 16;
            char* dst = (char*)CHL + (cur ^ 1) * TILE_BYTES + w * 4096;
            #pragma unroll
            for (int i = 0; i < 4; ++i)
                gload_lds16(src + i * 1024, dst + i * 1024);
        }

        const float4 cs0 = *(const float4*)&CSQ[kt * KTI + kg * 16 + grp4];

        f32x4_t acc[2];
        acc[0] = (f32x4_t){0.f, 0.f, 0.f, 0.f};
        acc[1] = (f32x4_t){0.f, 0.f, 0.f, 0.f};

        #pragma unroll
        for (int ks = 0; ks < 4; ++ks) {
            const int chunk = ks * 4 + (l >> 4);
            const int row = kg * 16 + (l & 15);
            const int byt = row * 256 + ((chunk ^ (row & 7)) * 16);
            bf16x8_t ah = *(bf16x8_t*)(buf + byt);
            bf16x8_t al = *(bf16x8_t*)(buf + 16384 + byt);
            #pragma unroll
            for (int qt = 0; qt < 2; ++qt) {
                acc[qt] = MFMA(ah, as_bf(zh[qt][ks]), acc[qt]);
                acc[qt] = MFMA(ah, as_bf(zl[qt][ks]), acc[qt]);
                acc[qt] = MFMA(al, as_bf(zh[qt][ks]), acc[qt]);
            }
        }

        // scores + per-lane top-2 (ascending k; strict < keeps earliest)
        #pragma unroll
        for (int qt = 0; qt < 2; ++qt)
            #pragma unroll
            for (int r = 0; r < 4; ++r) {
                int k = kt * KTI + kg * 16 + grp4 + r;
                float s = fmaf(-2.f, acc[qt][r], ((const float*)&cs0)[r]);
                if (s < s1[qt])      { s2[qt] = s1[qt]; i2[qt] = i1[qt]; s1[qt] = s; i1[qt] = k; }
                else if (s < s2[qt]) { s2[qt] = s; i2[qt] = k; }
            }

        __syncthreads();   // staging done (implicit vmcnt drain); readers of buf done
    }

    // intra-wave lex merge across the 4 lane-groups holding the same q
    #pragma unroll
    for (int qt = 0; qt < 2; ++qt) {
        float a1 = s1[qt], a2 = s2[qt];
        int j1 = i1[qt], j2 = i2[qt];
        #pragma unroll
        for (int off = 16; off < 64; off <<= 1) {
            float b1 = __shfl_xor(a1, off);
            float b2 = __shfl_xor(a2, off);
            int m1 = __shfl_xor(j1, off);
            int m2 = __shfl_xor(j2, off);
            bool bw = (b1 < a1) || (b1 == a1 && m1 < j1);
            float w1 = bw ? b1 : a1; int x1 = bw ? m1 : j1;
            float lb = bw ? a1 : b1; int ly = bw ? j1 : m1;   // loser's best
            float ws = bw ? b2 : a2; int wy = bw ? m2 : j2;   // winner's 2nd
            bool sw = (lb < ws) || (lb == ws && ly < wy);
            a1 = w1; j1 = x1;
            a2 = sw ? lb : ws; j2 = sw ? ly : wy;
        }
        if (l < 16)
            RED[kg][qgrp * 32 + qt * 16 + l] =
                make_float4(a1, __int_as_float(j1), a2, __int_as_float(j2));
    }
    __syncthreads();

    // final merge across 4 k-groups + exact fp32 refine (one thread per q)
    if (t < QTI) {
        float4 e = RED[0][t];
        float a1 = e.x, a2 = e.z;
        int j1 = __float_as_int(e.y), j2 = __float_as_int(e.w);
        #pragma unroll
        for (int g = 1; g < 4; ++g) {
            float4 f = RED[g][t];
            float b1 = f.x, b2 = f.z;
            int m1 = __float_as_int(f.y), m2 = __float_as_int(f.w);
            bool bw = (b1 < a1) || (b1 == a1 && m1 < j1);
            float w1 = bw ? b1 : a1; int x1 = bw ? m1 : j1;
            float lb = bw ? a1 : b1; int ly = bw ? j1 : m1;
            float ws = bw ? b2 : a2; int wy = bw ? m2 : j2;
            bool sw = (lb < ws) || (lb == ws && ly < wy);
            a1 = w1; j1 = x1;
            a2 = sw ? lb : ws; j2 = sw ? ly : wy;
        }
        const float* zr = z + (size_t)(qbase + t) * DIM;
        const float* c1 = cb + (size_t)j1 * DIM;
        const float* c2 = cb + (size_t)j2 * DIM;
        float p1 = 0.f, q1 = 0.f, p2 = 0.f, q2 = 0.f;
        #pragma unroll
        for (int d = 0; d < DIM; d += 4) {
            float4 zv = *(const float4*)(zr + d);
            float4 u = *(const float4*)(c1 + d);
            float4 v = *(const float4*)(c2 + d);
            p1 = fmaf(zv.x, u.x, p1); q1 = fmaf(zv.y, u.y, q1);
            p1 = fmaf(zv.z, u.z, p1); q1 = fmaf(zv.w, u.w, q1);
            p2 = fmaf(zv.x, v.x, p2); q2 = fmaf(zv.y, v.y, q2);
            p2 = fmaf(zv.z, v.z, p2); q2 = fmaf(zv.w, v.w, q2);
        }
        float e1 = fmaf(-2.f, p1 + q1, CSQ[j1]);
        float e2 = fmaf(-2.f, p2 + q2, CSQ[j2]);
        KWIN[t] = (e1 < e2 || (e1 == e2 && j1 < j2)) ? j1 : j2;
    }
    __syncthreads();

    {   // gather winning codebook rows (8 threads per row)
        const int srow = t >> 3;
        const int scol = t & 7;
        const float4* src = (const float4*)(cb + (size_t)KWIN[srow] * DIM);
        float4* dst = (float4*)(out + (size_t)(qbase + srow) * DIM);
        #pragma unroll
        for (int i = 0; i < 4; ++i) dst[scol + 8 * i] = src[scol + 8 * i];
    }
}

extern "C" void kernel_launch(void* const* d_in, const int* in_sizes, int n_in,
                              void* d_out, int out_size, void* d_ws, size_t ws_size,
                              hipStream_t stream) {
    const float* z  = (const float*)d_in[0];   // inputs [32,32,32,128]
    const float* cb = (const float*)d_in[1];   // codebook [1024,128]
    float* csq = (float*)d_ws;                             // 4 KB
    unsigned short* cws = (unsigned short*)((char*)d_ws + 4096);  // 512 KB split codebook
    float* out = (float*)d_out;

    vq_prep_kernel<<<KCB / 16, 256, 0, stream>>>(cb, csq, cws);
    vq_mfma_kernel<<<NQ / QTI, 512, 0, stream>>>(z, cb, cws, csq, out);
}